// Round 3
// baseline (4084.863 us; speedup 1.0000x reference)
//
#include <hip/hip_runtime.h>
#include <stdint.h>

#define BB 256
#define SS 64
#define TT 20
#define HH 1024
#define EE 100
#define G3 3072
#define G4 4096
#define KE 1152     // 1024 + 128 (E padded to 128)
#define VV 32000

typedef unsigned short ushort_t;
typedef short bf16x8 __attribute__((ext_vector_type(8)));
typedef float f32x4 __attribute__((ext_vector_type(4)));

#define DEV static __device__ __forceinline__

DEV ushort_t f2bf(float x) {
    union { float f; uint32_t u; } c; c.f = x;
    uint32_t r = (c.u + 0x7fffu + ((c.u >> 16) & 1u)) >> 16;
    return (ushort_t)r;
}
DEV float sigm(float x) { return 1.f / (1.f + expf(-x)); }

DEV void storeC(float* p, float v) { *p = v; }
DEV void storeC(ushort_t* p, float v) { *p = f2bf(v); }

#define MFMA16(a, b, c) __builtin_amdgcn_mfma_f32_16x16x32_bf16(a, b, c, 0, 0, 0)

// ---------------------------------------------------------------------------
// Prep: build bf16 W_enc_big [4096][1152] and W_dec_pad [3072][1152] from fp32
// W_enc_big rows: 0..2047  = [W_hh_e rows | W_ih_e rows (pad 100->128)]  (r,z)
//                 2048..3071 = [W_hh_e rows | 0]                          (hn)
//                 3072..4095 = [0 | W_ih_e rows 2048..3071 pad]           (inn)
// W_dec_pad rows n: [W_ih_d[n][0:100] pad -> 128 | W_ih_d[n][100:1124]]
// ---------------------------------------------------------------------------
__global__ void prep_w(const float* __restrict__ W_hh_e, const float* __restrict__ W_ih_e,
                       const float* __restrict__ W_ih_d,
                       ushort_t* __restrict__ W_enc_big, ushort_t* __restrict__ W_dec_pad) {
    int idx = blockIdx.x * 256 + threadIdx.x;
    const int NE = G4 * KE;
    if (idx < NE) {
        int n = idx / KE, k = idx - n * KE;
        ushort_t v = 0;
        if (k < HH) {
            if (n < G3) v = f2bf(W_hh_e[n * HH + k]);
        } else {
            int kk = k - HH;
            if (kk < EE) {
                if (n < 2048) v = f2bf(W_ih_e[n * EE + kk]);
                else if (n >= G3) v = f2bf(W_ih_e[(n - HH) * EE + kk]);
            }
        }
        W_enc_big[idx] = v;
    } else {
        int i2 = idx - NE;
        if (i2 < G3 * KE) {
            int n = i2 / KE, k = i2 - n * KE;
            ushort_t v;
            if (k < 128) v = (k < EE) ? f2bf(W_ih_d[n * 1124 + k]) : (ushort_t)0;
            else         v = f2bf(W_ih_d[n * 1124 + EE + (k - 128)]);
            W_dec_pad[i2] = v;
        }
    }
}

// fp32 -> bf16 copies of W_hh_d [3072][1024] and W_fc [32000][1024]
__global__ void conv_w(const float* __restrict__ W_hh_d, const float* __restrict__ W_fc,
                       ushort_t* __restrict__ W_hhd_b, ushort_t* __restrict__ W_fc_b) {
    int idx = blockIdx.x * 256 + threadIdx.x;
    const int N1 = G3 * HH;
    if (idx < N1) W_hhd_b[idx] = f2bf(W_hh_d[idx]);
    else {
        int i2 = idx - N1;
        if (i2 < VV * HH) W_fc_b[i2] = f2bf(W_fc[i2]);
    }
}

// ---------------------------------------------------------------------------
// Prep: emb_pad [64][256][128] bf16, A_enc init [256][1152] = [h0 | emb_0],
//       h_enc fp32, A_dec demb part [19][256][128 of 1152], ce_sum = 0
// ---------------------------------------------------------------------------
__global__ void prep_x(const int* __restrict__ inputs, const int* __restrict__ targets,
                       const float* __restrict__ h0, const float* __restrict__ E_enc,
                       const float* __restrict__ E_dec,
                       ushort_t* __restrict__ emb_pad, ushort_t* __restrict__ A_enc,
                       float* __restrict__ h_enc, ushort_t* __restrict__ A_dec,
                       float* __restrict__ ce_sum) {
    int idx = blockIdx.x * 256 + threadIdx.x;
    const int R0 = SS * BB * 128;            // emb_pad
    const int R1 = R0 + BB * KE;             // A_enc
    const int R2 = R1 + BB * HH;             // h_enc
    const int R3 = R2 + (TT - 1) * BB * 128; // A_dec demb
    const int R4 = R3 + 32;                  // ce_sum
    if (idx < R0) {
        int s = idx >> 15;           // /(256*128)
        int r = idx & 32767;
        int b = r >> 7, k = r & 127;
        emb_pad[idx] = (k < EE) ? f2bf(E_enc[(size_t)inputs[b * SS + s] * EE + k]) : (ushort_t)0;
    } else if (idx < R1) {
        int i = idx - R0;
        int b = i / KE, c = i - b * KE;
        ushort_t v;
        if (c < HH) v = f2bf(h0[b * HH + c]);
        else { int kk = c - HH; v = (kk < EE) ? f2bf(E_enc[(size_t)inputs[b * SS] * EE + kk]) : (ushort_t)0; }
        A_enc[i] = v;
    } else if (idx < R2) {
        int i = idx - R1;
        h_enc[i] = h0[i];
    } else if (idx < R3) {
        int i = idx - R2;
        int t = i >> 15;
        int r = i & 32767;
        int b = r >> 7, k = r & 127;
        int tok = (t == 0) ? 1 : targets[b * TT + t];
        A_dec[((size_t)(t * BB + b)) * KE + k] = (k < EE) ? f2bf(E_dec[(size_t)tok * EE + k]) : (ushort_t)0;
    } else if (idx < R4) {
        int i = idx - R3;
        ce_sum[i] = 0.f;
    }
}

// ---------------------------------------------------------------------------
// Direct-load wave GEMM: C[M,N] fp32 = A[M,K](bf16) * W[N,K]^T(bf16)
// wave tile 32x32 (2x2 subtiles of 16x16). For the small sequential GEMMs.
// ---------------------------------------------------------------------------
__global__ __launch_bounds__(256) void gemm_wave(const ushort_t* __restrict__ A,
                                                 const ushort_t* __restrict__ W,
                                                 float* __restrict__ C,
                                                 int M, int N, int K, int lda, int ldw, int ldc) {
    int lane = threadIdx.x & 63;
    int wid = blockIdx.x * 4 + (threadIdx.x >> 6);
    int tn = N >> 5;
    int total = (M >> 5) * tn;
    if (wid >= total) return;
    int mt = wid / tn, nt = wid - mt * tn;
    int m0 = mt << 5, n0 = nt << 5;
    int r16 = lane & 15, q8 = (lane >> 4) << 3;
    const ushort_t* ap0 = A + (size_t)(m0 + r16) * lda + q8;
    const ushort_t* ap1 = ap0 + (size_t)16 * lda;
    const ushort_t* wp0 = W + (size_t)(n0 + r16) * ldw + q8;
    const ushort_t* wp1 = wp0 + (size_t)16 * ldw;
    f32x4 acc00 = {0.f, 0.f, 0.f, 0.f}, acc01 = acc00, acc10 = acc00, acc11 = acc00;
    for (int k0 = 0; k0 < K; k0 += 32) {
        bf16x8 b0 = *(const bf16x8*)(wp0 + k0);
        bf16x8 b1 = *(const bf16x8*)(wp1 + k0);
        bf16x8 a0 = *(const bf16x8*)(ap0 + k0);
        bf16x8 a1 = *(const bf16x8*)(ap1 + k0);
        acc00 = MFMA16(a0, b0, acc00);
        acc01 = MFMA16(a0, b1, acc01);
        acc10 = MFMA16(a1, b0, acc10);
        acc11 = MFMA16(a1, b1, acc11);
    }
    int rbase = (lane >> 4) << 2;
    float* c0 = C + (size_t)(m0 + rbase) * ldc + n0 + r16;
#pragma unroll
    for (int r = 0; r < 4; ++r) {
        c0[(size_t)r * ldc] = acc00[r];
        c0[(size_t)r * ldc + 16] = acc01[r];
        c0[(size_t)(16 + r) * ldc] = acc10[r];
        c0[(size_t)(16 + r) * ldc + 16] = acc11[r];
    }
}

// ---------------------------------------------------------------------------
// 128x128 LDS-tiled MFMA GEMM (m93-style): C[M,N] = A[M,K](bf16) * W[N,K]^T
// grid: (N/128, M/128); block 256 threads (4 waves, 2x2 quadrants of 64x64)
// ---------------------------------------------------------------------------
template <typename OutT>
__global__ __launch_bounds__(256) void gemm128(const ushort_t* __restrict__ A,
                                               const ushort_t* __restrict__ W,
                                               OutT* __restrict__ C,
                                               int K, int lda, int ldw, int ldc) {
    __shared__ ushort_t As[128 * 32];
    __shared__ ushort_t Bs[128 * 32];
    int tid = threadIdx.x;
    int lane = tid & 63, wave = tid >> 6;
    int m0 = blockIdx.y << 7, n0 = blockIdx.x << 7;
    int row0 = tid >> 2, kc0 = (tid & 3) << 3;
    int row1 = row0 + 64;
    const ushort_t* a0p = A + (size_t)(m0 + row0) * lda + kc0;
    const ushort_t* a1p = A + (size_t)(m0 + row1) * lda + kc0;
    const ushort_t* w0p = W + (size_t)(n0 + row0) * ldw + kc0;
    const ushort_t* w1p = W + (size_t)(n0 + row1) * ldw + kc0;
    int mq = (wave >> 1) << 6, nq = (wave & 1) << 6;
    int r16 = lane & 15, q8 = (lane >> 4) << 3;
    const int lds0 = tid * 8, lds1 = tid * 8 + 2048;
    f32x4 zero4 = {0.f, 0.f, 0.f, 0.f};
    f32x4 acc[4][4];
#pragma unroll
    for (int i = 0; i < 4; ++i)
#pragma unroll
        for (int j = 0; j < 4; ++j) acc[i][j] = zero4;

    for (int k0 = 0; k0 < K; k0 += 32) {
        int4 va0 = *(const int4*)(a0p + k0);
        int4 va1 = *(const int4*)(a1p + k0);
        int4 vb0 = *(const int4*)(w0p + k0);
        int4 vb1 = *(const int4*)(w1p + k0);
        __syncthreads();
        *(int4*)(As + lds0) = va0;
        *(int4*)(As + lds1) = va1;
        *(int4*)(Bs + lds0) = vb0;
        *(int4*)(Bs + lds1) = vb1;
        __syncthreads();
        bf16x8 af[4], bfv[4];
#pragma unroll
        for (int i = 0; i < 4; ++i) af[i] = *(const bf16x8*)(As + ((mq + i * 16 + r16) << 5) + q8);
#pragma unroll
        for (int j = 0; j < 4; ++j) bfv[j] = *(const bf16x8*)(Bs + ((nq + j * 16 + r16) << 5) + q8);
#pragma unroll
        for (int i = 0; i < 4; ++i)
#pragma unroll
            for (int j = 0; j < 4; ++j) acc[i][j] = MFMA16(af[i], bfv[j], acc[i][j]);
    }
    int rbase = (lane >> 4) << 2;
#pragma unroll
    for (int i = 0; i < 4; ++i)
#pragma unroll
        for (int j = 0; j < 4; ++j)
#pragma unroll
            for (int r = 0; r < 4; ++r)
                storeC(&C[(size_t)(m0 + mq + i * 16 + rbase + r) * ldc + (n0 + nq + j * 16 + r16)],
                       acc[i][j][r]);
}

// ---------------------------------------------------------------------------
// Encoder GRU cell + context select + A_enc refresh (h part + next emb part)
// gates [256][4096]: [r_comb | z_comb | hn(hh only) | inn(ih only)] pre-bias
// biases fp32
// ---------------------------------------------------------------------------
__global__ void enc_cell(const float* __restrict__ gates, const float* __restrict__ bi,
                         const float* __restrict__ bh, float* __restrict__ h,
                         ushort_t* __restrict__ A_enc, const ushort_t* __restrict__ emb_pad,
                         const int* __restrict__ lengths, float* __restrict__ ctx_f,
                         ushort_t* __restrict__ ctx_b, int s) {
    int idx = blockIdx.x * 256 + threadIdx.x;  // 256*1152
    int b = idx / KE, c = idx - b * KE;
    if (c < HH) {
        int j = c;
        const float* g = gates + (size_t)b * G4;
        float r = sigm(g[j] + bi[j] + bh[j]);
        float z = sigm(g[HH + j] + bi[HH + j] + bh[HH + j]);
        float hn = g[2 * HH + j] + bh[2 * HH + j];
        float inn = g[3 * HH + j] + bi[2 * HH + j];
        float n = tanhf(inn + r * hn);
        int hi = b * HH + j;
        float hp = h[hi];
        float h2 = (1.f - z) * n + z * hp;
        h[hi] = h2;
        A_enc[(size_t)b * KE + j] = f2bf(h2);
        if (lengths[b] - 1 == s) { ctx_f[hi] = h2; ctx_b[hi] = f2bf(h2); }
    } else {
        int kk = c - HH;
        if (s + 1 < SS) A_enc[(size_t)b * KE + HH + kk] = emb_pad[(size_t)((s + 1) * BB + b) * 128 + kk];
    }
}

// Fill A_dec ctx columns for all 19 steps; init decoder h from context
__global__ void fill_ctx(const float* __restrict__ ctx_f, const ushort_t* __restrict__ ctx_b,
                         ushort_t* __restrict__ A_dec, float* __restrict__ h_dec,
                         ushort_t* __restrict__ h_dec_b) {
    int idx = blockIdx.x * 256 + threadIdx.x;  // 19*256*1024
    int t = idx >> 18;
    int r = idx & 262143;  // b*1024 + k
    ushort_t v = ctx_b[r];
    int b = r >> 10;
    int k = r & 1023;
    A_dec[((size_t)(t * BB + b)) * KE + 128 + k] = v;
    if (t == 0) { h_dec[r] = ctx_f[r]; h_dec_b[r] = v; }
}

// Decoder GRU cell: gh fp32 (hidden side, pre-bias), gi bf16 (input side, pre-bias)
__global__ void dec_cell(const float* __restrict__ gh, const ushort_t* __restrict__ gi,
                         const float* __restrict__ bi, const float* __restrict__ bh,
                         float* __restrict__ h, ushort_t* __restrict__ hb) {
    int idx = blockIdx.x * 256 + threadIdx.x;  // 256*1024
    int b = idx >> 10, j = idx & 1023;
    const float* g = gh + (size_t)b * G3;
    const ushort_t* gb = gi + (size_t)b * G3;
    union { uint32_t u; float f; } c0, c1, c2;
    c0.u = ((uint32_t)gb[j]) << 16;
    c1.u = ((uint32_t)gb[HH + j]) << 16;
    c2.u = ((uint32_t)gb[2 * HH + j]) << 16;
    float r = sigm(g[j] + bh[j] + c0.f + bi[j]);
    float z = sigm(g[HH + j] + bh[HH + j] + c1.f + bi[HH + j]);
    float hn = g[2 * HH + j] + bh[2 * HH + j];
    float inn = c2.f + bi[2 * HH + j];
    float n = tanhf(inn + r * hn);
    float hp = h[idx];
    float h2 = (1.f - z) * n + z * hp;
    h[idx] = h2;
    hb[idx] = f2bf(h2);
}

// Per-row logsumexp + CE accumulation: one block per batch row; bias fp32
__global__ __launch_bounds__(256) void ce_kernel(const float* __restrict__ logits,
                                                 const float* __restrict__ bfc,
                                                 const int* __restrict__ targets,
                                                 float* __restrict__ ce_sum, int t) {
    __shared__ float red[256];
    int b = blockIdx.x, tid = threadIdx.x;
    const float* row = logits + (size_t)b * VV;
    float mx = -3.0e38f;
    for (int v = tid; v < VV; v += 256) mx = fmaxf(mx, row[v] + bfc[v]);
    red[tid] = mx;
    __syncthreads();
    for (int s2 = 128; s2 > 0; s2 >>= 1) {
        if (tid < s2) red[tid] = fmaxf(red[tid], red[tid + s2]);
        __syncthreads();
    }
    mx = red[0];
    __syncthreads();
    float sm = 0.f;
    for (int v = tid; v < VV; v += 256) sm += expf(row[v] + bfc[v] - mx);
    red[tid] = sm;
    __syncthreads();
    for (int s2 = 128; s2 > 0; s2 >>= 1) {
        if (tid < s2) red[tid] += red[tid + s2];
        __syncthreads();
    }
    if (tid == 0) {
        int y = targets[b * TT + t + 1];
        float xt = row[y] + bfc[y];
        atomicAdd(&ce_sum[t], mx + logf(red[0]) - xt);
    }
}

// loss = (1/T) * sum_t (ce_sum[t]/B) * (mask_sum[t]/B)  -- OUTPUT IS FLOAT32
__global__ void finalize(const float* __restrict__ ce_sum, const int* __restrict__ targets,
                         float* __restrict__ out) {
    int lane = threadIdx.x;
    float term = 0.f;
    if (lane < TT - 1) {
        int msum = 0;
        for (int b = 0; b < BB; ++b) msum += (targets[b * TT + lane + 1] >= 1) ? 1 : 0;
        term = (ce_sum[lane] * (1.f / BB)) * ((float)msum * (1.f / BB));
    }
    for (int off = 32; off > 0; off >>= 1) term += __shfl_down(term, off, 64);
    if (lane == 0) out[0] = term * (1.f / TT);
}

extern "C" void kernel_launch(void* const* d_in, const int* in_sizes, int n_in,
                              void* d_out, int out_size, void* d_ws, size_t ws_size,
                              hipStream_t stream) {
    const int* inputs = (const int*)d_in[0];
    const int* targets = (const int*)d_in[1];
    const int* lengths = (const int*)d_in[2];
    const float* h0 = (const float*)d_in[3];
    const float* E_enc = (const float*)d_in[4];
    const float* E_dec = (const float*)d_in[5];
    const float* W_ih_e = (const float*)d_in[6];
    const float* W_hh_e = (const float*)d_in[7];
    const float* b_ih_e = (const float*)d_in[8];
    const float* b_hh_e = (const float*)d_in[9];
    const float* W_ih_d = (const float*)d_in[10];
    const float* W_hh_d = (const float*)d_in[11];
    const float* b_ih_d = (const float*)d_in[12];
    const float* b_hh_d = (const float*)d_in[13];
    const float* W_fc = (const float*)d_in[14];
    const float* b_fc = (const float*)d_in[15];

    char* ws = (char*)d_ws;
    size_t off = 0;
    auto alloc = [&](size_t bytes) -> char* {
        char* p = ws + off;
        off += (bytes + 255) & ~(size_t)255;
        return p;
    };
    ushort_t* W_enc_big = (ushort_t*)alloc((size_t)G4 * KE * 2);        // 9.4 MB
    ushort_t* W_dec_pad = (ushort_t*)alloc((size_t)G3 * KE * 2);        // 7.1 MB
    ushort_t* W_hhd_b = (ushort_t*)alloc((size_t)G3 * HH * 2);          // 6.3 MB
    ushort_t* W_fc_b = (ushort_t*)alloc((size_t)VV * HH * 2);           // 65.5 MB
    ushort_t* emb_pad = (ushort_t*)alloc((size_t)SS * BB * 128 * 2);    // 4.2 MB
    ushort_t* A_enc = (ushort_t*)alloc((size_t)BB * KE * 2);
    ushort_t* A_dec = (ushort_t*)alloc((size_t)(TT - 1) * BB * KE * 2); // 11.2 MB
    ushort_t* gi_dec = (ushort_t*)alloc((size_t)(TT - 1) * BB * G3 * 2);// 29.9 MB
    float* h_enc = (float*)alloc((size_t)BB * HH * 4);
    float* ctx_f = (float*)alloc((size_t)BB * HH * 4);
    ushort_t* ctx_b = (ushort_t*)alloc((size_t)BB * HH * 2);
    float* h_dec = (float*)alloc((size_t)BB * HH * 4);
    ushort_t* h_dec_b = (ushort_t*)alloc((size_t)BB * HH * 2);
    float* gates = (float*)alloc((size_t)BB * G4 * 4);                  // 4.2 MB
    float* logits = (float*)alloc((size_t)BB * VV * 4);                 // 32.8 MB
    float* ce_sum = (float*)alloc(64 * 4);
    // total ~176 MB

    // ---- prep ----
    {
        int nw = G4 * KE + G3 * KE;
        prep_w<<<(nw + 255) / 256, 256, 0, stream>>>(W_hh_e, W_ih_e, W_ih_d, W_enc_big, W_dec_pad);
        int nc = G3 * HH + VV * HH;
        conv_w<<<(nc + 255) / 256, 256, 0, stream>>>(W_hh_d, W_fc, W_hhd_b, W_fc_b);
        int nx = SS * BB * 128 + BB * KE + BB * HH + (TT - 1) * BB * 128 + 32;
        prep_x<<<(nx + 255) / 256, 256, 0, stream>>>(inputs, targets, h0, E_enc, E_dec,
                                                     emb_pad, A_enc, h_enc, A_dec, ce_sum);
    }

    // ---- encoder: 64 sequential steps ----
    for (int s = 0; s < SS; ++s) {
        gemm_wave<<<256, 256, 0, stream>>>(A_enc, W_enc_big, gates, BB, G4, KE, KE, KE, G4);
        enc_cell<<<(BB * KE) / 256, 256, 0, stream>>>(gates, b_ih_e, b_hh_e, h_enc, A_enc,
                                                      emb_pad, lengths, ctx_f, ctx_b, s);
    }

    // ---- decoder input-side gates (h-independent): one big GEMM ----
    fill_ctx<<<((TT - 1) * BB * HH) / 256, 256, 0, stream>>>(ctx_f, ctx_b, A_dec, h_dec, h_dec_b);
    gemm128<ushort_t><<<dim3(G3 / 128, (TT - 1) * BB / 128), 256, 0, stream>>>(
        A_dec, W_dec_pad, gi_dec, KE, KE, KE, G3);

    // ---- decoder: 19 sequential steps ----
    for (int t = 0; t < TT - 1; ++t) {
        gemm_wave<<<192, 256, 0, stream>>>(h_dec_b, W_hhd_b, gates, BB, G3, HH, HH, HH, G3);
        dec_cell<<<(BB * HH) / 256, 256, 0, stream>>>(gates, gi_dec + (size_t)t * BB * G3,
                                                      b_ih_d, b_hh_d, h_dec, h_dec_b);
        gemm128<float><<<dim3(VV / 128, BB / 128), 256, 0, stream>>>(
            h_dec_b, W_fc_b, logits, HH, HH, HH, VV);
        ce_kernel<<<BB, 256, 0, stream>>>(logits, b_fc, targets, ce_sum, t);
    }

    finalize<<<1, 64, 0, stream>>>(ce_sum, targets, (float*)d_out);
}

// Round 4
// 2758.552 us; speedup vs baseline: 1.4808x; 1.4808x over previous
//
#include <hip/hip_runtime.h>
#include <stdint.h>

#define BB 256
#define SS 64
#define TT 20
#define HH 1024
#define EE 100
#define G3 3072
#define G4 4096
#define KE 1152     // 1024 + 128 (E padded to 128)
#define VV 32000

typedef unsigned short ushort_t;
typedef short bf16x8 __attribute__((ext_vector_type(8)));
typedef float f32x4 __attribute__((ext_vector_type(4)));

#define DEV static __device__ __forceinline__

DEV float bf2f(ushort_t h) {
    union { uint32_t u; float f; } c; c.u = ((uint32_t)h) << 16; return c.f;
}
DEV ushort_t f2bf(float x) {
    union { float f; uint32_t u; } c; c.f = x;
    uint32_t r = (c.u + 0x7fffu + ((c.u >> 16) & 1u)) >> 16;
    return (ushort_t)r;
}
DEV float sigm(float x) { return 1.f / (1.f + expf(-x)); }

DEV void storeC(float* p, float v) { *p = v; }
DEV void storeC(ushort_t* p, float v) { *p = f2bf(v); }

#define MFMA16(a, b, c) __builtin_amdgcn_mfma_f32_16x16x32_bf16(a, b, c, 0, 0, 0)

// ---------------------------------------------------------------------------
// prep_w: build bf16 W_enc_big [4096][1152], W_dec_pad [3072][1152] from fp32.
// W_enc_big rows: 0..1023 r (hh|ih), 1024..2047 z (hh|ih), 2048..3071 hn (hh|0),
//                 3072..4095 inn (0|ih).  Vector 16B stores, 8 elems/thread.
// ---------------------------------------------------------------------------
__global__ void prep_w(const float* __restrict__ W_hh_e, const float* __restrict__ W_ih_e,
                       const float* __restrict__ W_ih_d,
                       ushort_t* __restrict__ W_enc_big, ushort_t* __restrict__ W_dec_pad) {
    int idx = blockIdx.x * 256 + threadIdx.x;  // (G4+G3) * (KE/8) = 7168*144
    int n = idx / 144, kc = (idx - n * 144) * 8;
    ushort_t o[8];
    if (n < G4) {
        if (kc < HH) {
            if (n < G3) {
#pragma unroll
                for (int u = 0; u < 8; ++u) o[u] = f2bf(W_hh_e[(size_t)n * HH + kc + u]);
            } else {
#pragma unroll
                for (int u = 0; u < 8; ++u) o[u] = 0;
            }
        } else {
            int kk = kc - HH;
#pragma unroll
            for (int u = 0; u < 8; ++u) {
                int k2 = kk + u;
                ushort_t v = 0;
                if (k2 < EE) {
                    if (n < 2048) v = f2bf(W_ih_e[(size_t)n * EE + k2]);
                    else if (n >= G3) v = f2bf(W_ih_e[(size_t)(n - HH) * EE + k2]);
                }
                o[u] = v;
            }
        }
        *(int4*)(W_enc_big + (size_t)n * KE + kc) = *(int4*)o;
    } else {
        int nd = n - G4;
        if (kc < 128) {
#pragma unroll
            for (int u = 0; u < 8; ++u) {
                int k2 = kc + u;
                o[u] = (k2 < EE) ? f2bf(W_ih_d[(size_t)nd * 1124 + k2]) : (ushort_t)0;
            }
        } else {
#pragma unroll
            for (int u = 0; u < 8; ++u) o[u] = f2bf(W_ih_d[(size_t)nd * 1124 + EE + (kc - 128) + u]);
        }
        *(int4*)(W_dec_pad + (size_t)nd * KE + kc) = *(int4*)o;
    }
}

// fp32 -> bf16 copies of W_hh_d [3072][1024] and W_fc [32000][1024]; 8 elems/thread
__global__ void conv_w(const float* __restrict__ W_hh_d, const float* __restrict__ W_fc,
                       ushort_t* __restrict__ W_hhd_b, ushort_t* __restrict__ W_fc_b) {
    int idx = blockIdx.x * 256 + threadIdx.x;
    const int N1 = G3 * HH / 8;
    const float* src;
    ushort_t* dst;
    size_t e;
    if (idx < N1) { e = (size_t)idx * 8; src = W_hh_d; dst = W_hhd_b; }
    else { e = (size_t)(idx - N1) * 8; src = W_fc; dst = W_fc_b; }
    float4 a = *(const float4*)(src + e);
    float4 b = *(const float4*)(src + e + 4);
    ushort_t o[8] = {f2bf(a.x), f2bf(a.y), f2bf(a.z), f2bf(a.w),
                     f2bf(b.x), f2bf(b.y), f2bf(b.z), f2bf(b.w)};
    *(int4*)(dst + e) = *(int4*)o;
}

// ---------------------------------------------------------------------------
// prep_x: emb_pad [64][256][128] bf16, A_enc0 = [h0 | emb_0], h_enc fp32,
//         A_dec demb part [19][256][128 of 1152], ce_sum = 0
// ---------------------------------------------------------------------------
__global__ void prep_x(const int* __restrict__ inputs, const int* __restrict__ targets,
                       const float* __restrict__ h0, const float* __restrict__ E_enc,
                       const float* __restrict__ E_dec,
                       ushort_t* __restrict__ emb_pad, ushort_t* __restrict__ A_enc,
                       float* __restrict__ h_enc, ushort_t* __restrict__ A_dec,
                       float* __restrict__ ce_sum) {
    int idx = blockIdx.x * 256 + threadIdx.x;
    const int R0 = SS * BB * 128;
    const int R1 = R0 + BB * KE;
    const int R2 = R1 + BB * HH;
    const int R3 = R2 + (TT - 1) * BB * 128;
    const int R4 = R3 + 32;
    if (idx < R0) {
        int s = idx >> 15;
        int r = idx & 32767;
        int b = r >> 7, k = r & 127;
        emb_pad[idx] = (k < EE) ? f2bf(E_enc[(size_t)inputs[b * SS + s] * EE + k]) : (ushort_t)0;
    } else if (idx < R1) {
        int i = idx - R0;
        int b = i / KE, c = i - b * KE;
        ushort_t v;
        if (c < HH) v = f2bf(h0[b * HH + c]);
        else { int kk = c - HH; v = (kk < EE) ? f2bf(E_enc[(size_t)inputs[b * SS] * EE + kk]) : (ushort_t)0; }
        A_enc[i] = v;
    } else if (idx < R2) {
        int i = idx - R1;
        h_enc[i] = h0[i];
    } else if (idx < R3) {
        int i = idx - R2;
        int t = i >> 15;
        int r = i & 32767;
        int b = r >> 7, k = r & 127;
        int tok = (t == 0) ? 1 : targets[b * TT + t];
        A_dec[((size_t)(t * BB + b)) * KE + k] = (k < EE) ? f2bf(E_dec[(size_t)tok * EE + k]) : (ushort_t)0;
    } else if (idx < R4) {
        ce_sum[idx - R3] = 0.f;
    }
}

// ---------------------------------------------------------------------------
// Fused encoder step: block = 64 batch rows x 32 hidden cols x 4 gate groups.
// Wave g computes group g's 64x32 gate tile (W rows g*1024+j). BK=64 LDS A
// staging + register-prefetched W frags. Epilogue: LDS gate exchange (stride
// 33 pad), GRU cell, writes h fp32 + next A (bf16, double-buffered) + context.
// ---------------------------------------------------------------------------
__global__ __launch_bounds__(256) void enc_step(
    const ushort_t* __restrict__ Ain, ushort_t* __restrict__ Aout,
    const ushort_t* __restrict__ W, const float* __restrict__ bi,
    const float* __restrict__ bh, float* __restrict__ h,
    const ushort_t* __restrict__ emb_pad, const int* __restrict__ lengths,
    float* __restrict__ ctx_f, ushort_t* __restrict__ ctx_b, int s) {
    __shared__ ushort_t As[64 * 64];
    __shared__ float gbuf[4][64 * 33];
    int tid = threadIdx.x;
    int lane = tid & 63, g = tid >> 6;
    int j0 = blockIdx.x << 5, m0 = blockIdx.y << 6;
    int r16 = lane & 15, q = lane >> 4, q8 = q << 3;
    int srow = tid >> 3, skc = (tid & 7) << 3;
    const ushort_t* ap0 = Ain + (size_t)(m0 + srow) * KE + skc;
    const ushort_t* ap1 = ap0 + (size_t)32 * KE;
    const int s0 = srow * 64 + skc, s1 = s0 + 32 * 64;
    const ushort_t* wb0 = W + (size_t)(g * 1024 + j0 + r16) * KE + q8;
    const ushort_t* wb1 = wb0 + (size_t)16 * KE;
    f32x4 zero = {0.f, 0.f, 0.f, 0.f};
    f32x4 acc[4][2];
#pragma unroll
    for (int i = 0; i < 4; ++i) { acc[i][0] = zero; acc[i][1] = zero; }
    bf16x8 wf00 = *(const bf16x8*)(wb0);
    bf16x8 wf01 = *(const bf16x8*)(wb1);
    bf16x8 wf10 = *(const bf16x8*)(wb0 + 32);
    bf16x8 wf11 = *(const bf16x8*)(wb1 + 32);
    for (int k0 = 0; k0 < KE; k0 += 64) {
        int4 va0 = *(const int4*)(ap0 + k0);
        int4 va1 = *(const int4*)(ap1 + k0);
        __syncthreads();
        *(int4*)(As + s0) = va0;
        *(int4*)(As + s1) = va1;
        int kn = (k0 + 64 < KE) ? k0 + 64 : 0;
        bf16x8 wn00 = *(const bf16x8*)(wb0 + kn);
        bf16x8 wn01 = *(const bf16x8*)(wb1 + kn);
        bf16x8 wn10 = *(const bf16x8*)(wb0 + kn + 32);
        bf16x8 wn11 = *(const bf16x8*)(wb1 + kn + 32);
        __syncthreads();
#pragma unroll
        for (int i = 0; i < 4; ++i) {
            bf16x8 af0 = *(const bf16x8*)(As + ((i * 16 + r16) << 6) + q8);
            bf16x8 af1 = *(const bf16x8*)(As + ((i * 16 + r16) << 6) + 32 + q8);
            acc[i][0] = MFMA16(af0, wf00, acc[i][0]);
            acc[i][1] = MFMA16(af0, wf01, acc[i][1]);
            acc[i][0] = MFMA16(af1, wf10, acc[i][0]);
            acc[i][1] = MFMA16(af1, wf11, acc[i][1]);
        }
        wf00 = wn00; wf01 = wn01; wf10 = wn10; wf11 = wn11;
    }
#pragma unroll
    for (int i = 0; i < 4; ++i)
#pragma unroll
        for (int j2 = 0; j2 < 2; ++j2)
#pragma unroll
            for (int r = 0; r < 4; ++r)
                gbuf[g][(i * 16 + q * 4 + r) * 33 + j2 * 16 + r16] = acc[i][j2][r];
    __syncthreads();
    // epilogue: thread -> (m = tid&63, 8 cols at (tid>>6)*8)
    int m = tid & 63, jc0 = (tid >> 6) << 3;
    int bgl = m0 + m, gj = j0 + jc0;
    int sel = (lengths[bgl] - 1 == s);
    const float* g0 = &gbuf[0][m * 33 + jc0];
    const float* g1 = &gbuf[1][m * 33 + jc0];
    const float* g2 = &gbuf[2][m * 33 + jc0];
    const float* g3 = &gbuf[3][m * 33 + jc0];
    ushort_t hb8[8];
#pragma unroll
    for (int u = 0; u < 8; ++u) {
        int jg = gj + u;
        float rr = sigm(g0[u] + bi[jg] + bh[jg]);
        float zz = sigm(g1[u] + bi[1024 + jg] + bh[1024 + jg]);
        float hn = g2[u] + bh[2048 + jg];
        float inn = g3[u] + bi[2048 + jg];
        float nn = tanhf(inn + rr * hn);
        size_t hi = (size_t)bgl * 1024 + jg;
        float hp = h[hi];
        float h2 = (1.f - zz) * nn + zz * hp;
        h[hi] = h2;
        hb8[u] = f2bf(h2);
        if (sel) { ctx_f[hi] = h2; ctx_b[hi] = hb8[u]; }
    }
    *(int4*)(Aout + (size_t)bgl * KE + gj) = *(int4*)hb8;
    // emb refresh for next step (only jt==0 blocks; writes to Aout's emb cols)
    if (blockIdx.x == 0 && s + 1 < SS) {
        int rr2 = tid >> 2, c0 = (tid & 3) << 5;
#pragma unroll
        for (int cc = 0; cc < 32; cc += 8) {
            int4 v = *(const int4*)(emb_pad + ((size_t)(s + 1) * BB + m0 + rr2) * 128 + c0 + cc);
            *(int4*)(Aout + (size_t)(m0 + rr2) * KE + 1024 + c0 + cc) = v;
        }
    }
}

// Fill A_dec ctx columns for all 19 steps; init decoder h (fp32) + hb0 (bf16)
__global__ void fill_ctx(const float* __restrict__ ctx_f, const ushort_t* __restrict__ ctx_b,
                         ushort_t* __restrict__ A_dec, float* __restrict__ h_dec,
                         ushort_t* __restrict__ hb0) {
    int idx = blockIdx.x * 256 + threadIdx.x;  // 19*256*1024
    int t = idx >> 18;
    int r = idx & 262143;
    ushort_t v = ctx_b[r];
    int b = r >> 10;
    int k = r & 1023;
    A_dec[((size_t)(t * BB + b)) * KE + 128 + k] = v;
    if (t == 0) { h_dec[r] = ctx_f[r]; hb0[r] = v; }
}

// ---------------------------------------------------------------------------
// 128x128 LDS-tiled MFMA GEMM (for the one big gi_dec GEMM)
// ---------------------------------------------------------------------------
template <typename OutT>
__global__ __launch_bounds__(256) void gemm128(const ushort_t* __restrict__ A,
                                               const ushort_t* __restrict__ W,
                                               OutT* __restrict__ C,
                                               int K, int lda, int ldw, int ldc) {
    __shared__ ushort_t As[128 * 32];
    __shared__ ushort_t Bs[128 * 32];
    int tid = threadIdx.x;
    int lane = tid & 63, wave = tid >> 6;
    int m0 = blockIdx.y << 7, n0 = blockIdx.x << 7;
    int row0 = tid >> 2, kc0 = (tid & 3) << 3;
    const ushort_t* a0p = A + (size_t)(m0 + row0) * lda + kc0;
    const ushort_t* a1p = A + (size_t)(m0 + row0 + 64) * lda + kc0;
    const ushort_t* w0p = W + (size_t)(n0 + row0) * ldw + kc0;
    const ushort_t* w1p = W + (size_t)(n0 + row0 + 64) * ldw + kc0;
    int mq = (wave >> 1) << 6, nq = (wave & 1) << 6;
    int r16 = lane & 15, q8 = (lane >> 4) << 3;
    const int lds0 = tid * 8, lds1 = tid * 8 + 2048;
    f32x4 zero4 = {0.f, 0.f, 0.f, 0.f};
    f32x4 acc[4][4];
#pragma unroll
    for (int i = 0; i < 4; ++i)
#pragma unroll
        for (int j = 0; j < 4; ++j) acc[i][j] = zero4;
    for (int k0 = 0; k0 < K; k0 += 32) {
        int4 va0 = *(const int4*)(a0p + k0);
        int4 va1 = *(const int4*)(a1p + k0);
        int4 vb0 = *(const int4*)(w0p + k0);
        int4 vb1 = *(const int4*)(w1p + k0);
        __syncthreads();
        *(int4*)(As + lds0) = va0;
        *(int4*)(As + lds1) = va1;
        *(int4*)(Bs + lds0) = vb0;
        *(int4*)(Bs + lds1) = vb1;
        __syncthreads();
        bf16x8 af[4], bfv[4];
#pragma unroll
        for (int i = 0; i < 4; ++i) af[i] = *(const bf16x8*)(As + ((mq + i * 16 + r16) << 5) + q8);
#pragma unroll
        for (int j = 0; j < 4; ++j) bfv[j] = *(const bf16x8*)(Bs + ((nq + j * 16 + r16) << 5) + q8);
#pragma unroll
        for (int i = 0; i < 4; ++i)
#pragma unroll
            for (int j = 0; j < 4; ++j) acc[i][j] = MFMA16(af[i], bfv[j], acc[i][j]);
    }
    int rbase = (lane >> 4) << 2;
#pragma unroll
    for (int i = 0; i < 4; ++i)
#pragma unroll
        for (int j = 0; j < 4; ++j)
#pragma unroll
            for (int r = 0; r < 4; ++r)
                storeC(&C[(size_t)(m0 + mq + i * 16 + rbase + r) * ldc + (n0 + nq + j * 16 + r16)],
                       acc[i][j][r]);
}

// ---------------------------------------------------------------------------
// Fused decoder recurrent step: like enc_step but 3 gate groups (wave 3 only
// stages/epilogues). gi (input-side gates, bf16) read in epilogue.
// ---------------------------------------------------------------------------
__global__ __launch_bounds__(256) void dec_step(
    const ushort_t* __restrict__ Ain, ushort_t* __restrict__ Aout,
    const ushort_t* __restrict__ W, const ushort_t* __restrict__ gi,
    const float* __restrict__ bi, const float* __restrict__ bh,
    float* __restrict__ h) {
    __shared__ ushort_t As[64 * 64];
    __shared__ float gbuf[3][64 * 33];
    int tid = threadIdx.x;
    int lane = tid & 63, g = tid >> 6;
    int j0 = blockIdx.x << 5, m0 = blockIdx.y << 6;
    int r16 = lane & 15, q = lane >> 4, q8 = q << 3;
    int srow = tid >> 3, skc = (tid & 7) << 3;
    const ushort_t* ap0 = Ain + (size_t)(m0 + srow) * HH + skc;
    const ushort_t* ap1 = ap0 + (size_t)32 * HH;
    const int s0 = srow * 64 + skc, s1 = s0 + 32 * 64;
    const ushort_t* wb0 = W + (size_t)(g * 1024 + j0 + r16) * HH + q8;
    const ushort_t* wb1 = wb0 + (size_t)16 * HH;
    f32x4 zero = {0.f, 0.f, 0.f, 0.f};
    f32x4 acc[4][2];
#pragma unroll
    for (int i = 0; i < 4; ++i) { acc[i][0] = zero; acc[i][1] = zero; }
    bf16x8 wf00 = {0,0,0,0,0,0,0,0}, wf01 = wf00, wf10 = wf00, wf11 = wf00;
    if (g < 3) {
        wf00 = *(const bf16x8*)(wb0);
        wf01 = *(const bf16x8*)(wb1);
        wf10 = *(const bf16x8*)(wb0 + 32);
        wf11 = *(const bf16x8*)(wb1 + 32);
    }
    for (int k0 = 0; k0 < HH; k0 += 64) {
        int4 va0 = *(const int4*)(ap0 + k0);
        int4 va1 = *(const int4*)(ap1 + k0);
        __syncthreads();
        *(int4*)(As + s0) = va0;
        *(int4*)(As + s1) = va1;
        bf16x8 wn00 = wf00, wn01 = wf01, wn10 = wf10, wn11 = wf11;
        if (g < 3) {
            int kn = (k0 + 64 < HH) ? k0 + 64 : 0;
            wn00 = *(const bf16x8*)(wb0 + kn);
            wn01 = *(const bf16x8*)(wb1 + kn);
            wn10 = *(const bf16x8*)(wb0 + kn + 32);
            wn11 = *(const bf16x8*)(wb1 + kn + 32);
        }
        __syncthreads();
        if (g < 3) {
#pragma unroll
            for (int i = 0; i < 4; ++i) {
                bf16x8 af0 = *(const bf16x8*)(As + ((i * 16 + r16) << 6) + q8);
                bf16x8 af1 = *(const bf16x8*)(As + ((i * 16 + r16) << 6) + 32 + q8);
                acc[i][0] = MFMA16(af0, wf00, acc[i][0]);
                acc[i][1] = MFMA16(af0, wf01, acc[i][1]);
                acc[i][0] = MFMA16(af1, wf10, acc[i][0]);
                acc[i][1] = MFMA16(af1, wf11, acc[i][1]);
            }
        }
        wf00 = wn00; wf01 = wn01; wf10 = wn10; wf11 = wn11;
    }
    if (g < 3) {
#pragma unroll
        for (int i = 0; i < 4; ++i)
#pragma unroll
            for (int j2 = 0; j2 < 2; ++j2)
#pragma unroll
                for (int r = 0; r < 4; ++r)
                    gbuf[g][(i * 16 + q * 4 + r) * 33 + j2 * 16 + r16] = acc[i][j2][r];
    }
    __syncthreads();
    int m = tid & 63, jc0 = (tid >> 6) << 3;
    int bgl = m0 + m, gj = j0 + jc0;
    const ushort_t* gip = gi + (size_t)bgl * G3;
    ushort_t gr[8], gz[8], gn[8], hb8[8];
    *(int4*)gr = *(const int4*)(gip + gj);
    *(int4*)gz = *(const int4*)(gip + 1024 + gj);
    *(int4*)gn = *(const int4*)(gip + 2048 + gj);
    const float* g0 = &gbuf[0][m * 33 + jc0];
    const float* g1 = &gbuf[1][m * 33 + jc0];
    const float* g2 = &gbuf[2][m * 33 + jc0];
#pragma unroll
    for (int u = 0; u < 8; ++u) {
        int jg = gj + u;
        float rr = sigm(g0[u] + bh[jg] + bf2f(gr[u]) + bi[jg]);
        float zz = sigm(g1[u] + bh[1024 + jg] + bf2f(gz[u]) + bi[1024 + jg]);
        float hn = g2[u] + bh[2048 + jg];
        float inn = bf2f(gn[u]) + bi[2048 + jg];
        float nn = tanhf(inn + rr * hn);
        size_t hi = (size_t)bgl * 1024 + jg;
        float hp = h[hi];
        float h2 = (1.f - zz) * nn + zz * hp;
        h[hi] = h2;
        hb8[u] = f2bf(h2);
    }
    *(int4*)(Aout + (size_t)bgl * 1024 + gj) = *(int4*)hb8;
}

// ---------------------------------------------------------------------------
// Fused logits GEMM + CE partials: never materializes logits. 128x128 tile;
// epilogue computes per-row (max, sumexp) over the block's 128 cols + grabs
// the target logit. part arrays: [row][256] (250 n-blocks used).
// ---------------------------------------------------------------------------
__global__ __launch_bounds__(256) void logits_ce(
    const ushort_t* __restrict__ A, const ushort_t* __restrict__ Wf,
    const float* __restrict__ bfc, const int* __restrict__ targets,
    float* __restrict__ part_max, float* __restrict__ part_sum,
    float* __restrict__ xt, int t) {
    __shared__ ushort_t As[128 * 32];
    __shared__ ushort_t Bs[128 * 32];
    __shared__ float wm[128][2], ws2[128][2];
    int tid = threadIdx.x;
    int lane = tid & 63, wave = tid >> 6;
    int n0 = blockIdx.x << 7, m0 = blockIdx.y << 7;
    int row0 = tid >> 2, kc0 = (tid & 3) << 3;
    const ushort_t* a0p = A + (size_t)(m0 + row0) * HH + kc0;
    const ushort_t* a1p = A + (size_t)(m0 + row0 + 64) * HH + kc0;
    const ushort_t* w0p = Wf + (size_t)(n0 + row0) * HH + kc0;
    const ushort_t* w1p = Wf + (size_t)(n0 + row0 + 64) * HH + kc0;
    int mq = (wave >> 1) << 6, nq = (wave & 1) << 6;
    int r16 = lane & 15, q = lane >> 4, q8 = q << 3;
    const int lds0 = tid * 8, lds1 = tid * 8 + 2048;
    f32x4 zero4 = {0.f, 0.f, 0.f, 0.f};
    f32x4 acc[4][4];
#pragma unroll
    for (int i = 0; i < 4; ++i)
#pragma unroll
        for (int j = 0; j < 4; ++j) acc[i][j] = zero4;
    for (int k0 = 0; k0 < HH; k0 += 32) {
        int4 va0 = *(const int4*)(a0p + k0);
        int4 va1 = *(const int4*)(a1p + k0);
        int4 vb0 = *(const int4*)(w0p + k0);
        int4 vb1 = *(const int4*)(w1p + k0);
        __syncthreads();
        *(int4*)(As + lds0) = va0;
        *(int4*)(As + lds1) = va1;
        *(int4*)(Bs + lds0) = vb0;
        *(int4*)(Bs + lds1) = vb1;
        __syncthreads();
        bf16x8 af[4], bfv[4];
#pragma unroll
        for (int i = 0; i < 4; ++i) af[i] = *(const bf16x8*)(As + ((mq + i * 16 + r16) << 5) + q8);
#pragma unroll
        for (int j = 0; j < 4; ++j) bfv[j] = *(const bf16x8*)(Bs + ((nq + j * 16 + r16) << 5) + q8);
#pragma unroll
        for (int i = 0; i < 4; ++i)
#pragma unroll
            for (int j = 0; j < 4; ++j) acc[i][j] = MFMA16(af[i], bfv[j], acc[i][j]);
    }
    float bias[4];
#pragma unroll
    for (int j2 = 0; j2 < 4; ++j2) bias[j2] = bfc[n0 + nq + j2 * 16 + r16];
    int nw = wave & 1;
#pragma unroll
    for (int i = 0; i < 4; ++i) {
#pragma unroll
        for (int r = 0; r < 4; ++r) {
            int rloc = mq + i * 16 + q * 4 + r;
            int brow = m0 + rloc;
            int y = targets[brow * TT + t + 1];
            float v[4];
            float mx = -3.0e38f;
#pragma unroll
            for (int j2 = 0; j2 < 4; ++j2) {
                v[j2] = acc[i][j2][r] + bias[j2];
                if (n0 + nq + j2 * 16 + r16 == y) xt[brow] = v[j2];
                mx = fmaxf(mx, v[j2]);
            }
#pragma unroll
            for (int d = 1; d < 16; d <<= 1) mx = fmaxf(mx, __shfl_xor(mx, d, 64));
            float se = 0.f;
#pragma unroll
            for (int j2 = 0; j2 < 4; ++j2) se += expf(v[j2] - mx);
#pragma unroll
            for (int d = 1; d < 16; d <<= 1) se += __shfl_xor(se, d, 64);
            if (r16 == 0) { wm[rloc][nw] = mx; ws2[rloc][nw] = se; }
        }
    }
    __syncthreads();
    if (tid < 128) {
        float m0v = wm[tid][0], m1v = wm[tid][1];
        float M = fmaxf(m0v, m1v);
        float S = ws2[tid][0] * expf(m0v - M) + ws2[tid][1] * expf(m1v - M);
        int brow = m0 + tid;
        part_max[(size_t)brow * 256 + blockIdx.x] = M;
        part_sum[(size_t)brow * 256 + blockIdx.x] = S;
    }
}

// Merge 250 per-row partials -> CE for the row; atomicAdd into ce_sum[t]
__global__ void ce_merge(const float* __restrict__ pm, const float* __restrict__ ps,
                         const float* __restrict__ xt, float* __restrict__ ce_sum, int t) {
    int row = blockIdx.x * 4 + (threadIdx.x >> 6);
    int lane = threadIdx.x & 63;
    const float* pmr = pm + (size_t)row * 256;
    const float* psr = ps + (size_t)row * 256;
    float lm[4];
    int cnt = 0;
    float mx = -3.0e38f;
    for (int i = lane; i < 250; i += 64) { float v = pmr[i]; lm[cnt++] = v; mx = fmaxf(mx, v); }
    for (int d = 1; d < 64; d <<= 1) mx = fmaxf(mx, __shfl_xor(mx, d, 64));
    float s = 0.f;
    cnt = 0;
    for (int i = lane; i < 250; i += 64) { s += psr[i] * expf(lm[cnt++] - mx); }
    for (int d = 1; d < 64; d <<= 1) s += __shfl_xor(s, d, 64);
    if (lane == 0) atomicAdd(&ce_sum[t], mx + logf(s) - xt[row]);
}

// loss = (1/T) * sum_t (ce_sum[t]/B) * (mask_sum[t]/B)  -- OUTPUT float32
__global__ void finalize(const float* __restrict__ ce_sum, const int* __restrict__ targets,
                         float* __restrict__ out) {
    int lane = threadIdx.x;
    float term = 0.f;
    if (lane < TT - 1) {
        int msum = 0;
        for (int b = 0; b < BB; ++b) msum += (targets[b * TT + lane + 1] >= 1) ? 1 : 0;
        term = (ce_sum[lane] * (1.f / BB)) * ((float)msum * (1.f / BB));
    }
    for (int off = 32; off > 0; off >>= 1) term += __shfl_down(term, off, 64);
    if (lane == 0) out[0] = term * (1.f / TT);
}

extern "C" void kernel_launch(void* const* d_in, const int* in_sizes, int n_in,
                              void* d_out, int out_size, void* d_ws, size_t ws_size,
                              hipStream_t stream) {
    const int* inputs = (const int*)d_in[0];
    const int* targets = (const int*)d_in[1];
    const int* lengths = (const int*)d_in[2];
    const float* h0 = (const float*)d_in[3];
    const float* E_enc = (const float*)d_in[4];
    const float* E_dec = (const float*)d_in[5];
    const float* W_ih_e = (const float*)d_in[6];
    const float* W_hh_e = (const float*)d_in[7];
    const float* b_ih_e = (const float*)d_in[8];
    const float* b_hh_e = (const float*)d_in[9];
    const float* W_ih_d = (const float*)d_in[10];
    const float* W_hh_d = (const float*)d_in[11];
    const float* b_ih_d = (const float*)d_in[12];
    const float* b_hh_d = (const float*)d_in[13];
    const float* W_fc = (const float*)d_in[14];
    const float* b_fc = (const float*)d_in[15];

    char* ws = (char*)d_ws;
    size_t off = 0;
    auto alloc = [&](size_t bytes) -> char* {
        char* p = ws + off;
        off += (bytes + 255) & ~(size_t)255;
        return p;
    };
    ushort_t* W_enc_big = (ushort_t*)alloc((size_t)G4 * KE * 2);
    ushort_t* W_dec_pad = (ushort_t*)alloc((size_t)G3 * KE * 2);
    ushort_t* W_hhd_b = (ushort_t*)alloc((size_t)G3 * HH * 2);
    ushort_t* W_fc_b = (ushort_t*)alloc((size_t)VV * HH * 2);
    ushort_t* emb_pad = (ushort_t*)alloc((size_t)SS * BB * 128 * 2);
    ushort_t* A_enc0 = (ushort_t*)alloc((size_t)BB * KE * 2);
    ushort_t* A_enc1 = (ushort_t*)alloc((size_t)BB * KE * 2);
    ushort_t* A_dec = (ushort_t*)alloc((size_t)(TT - 1) * BB * KE * 2);
    ushort_t* gi_dec = (ushort_t*)alloc((size_t)(TT - 1) * BB * G3 * 2);
    float* h_enc = (float*)alloc((size_t)BB * HH * 4);
    float* ctx_f = (float*)alloc((size_t)BB * HH * 4);
    ushort_t* ctx_b = (ushort_t*)alloc((size_t)BB * HH * 2);
    float* h_dec = (float*)alloc((size_t)BB * HH * 4);
    ushort_t* hb0 = (ushort_t*)alloc((size_t)BB * HH * 2);
    ushort_t* hb1 = (ushort_t*)alloc((size_t)BB * HH * 2);
    float* part_max = (float*)alloc((size_t)BB * 256 * 4);
    float* part_sum = (float*)alloc((size_t)BB * 256 * 4);
    float* xt = (float*)alloc((size_t)BB * 4);
    float* ce_sum = (float*)alloc(64 * 4);
    ushort_t* Aenc[2] = {A_enc0, A_enc1};
    ushort_t* hb[2] = {hb0, hb1};

    // ---- prep ----
    prep_w<<<(G4 + G3) * (KE / 8) / 256, 256, 0, stream>>>(W_hh_e, W_ih_e, W_ih_d,
                                                           W_enc_big, W_dec_pad);
    conv_w<<<(G3 * HH + VV * HH) / 8 / 256, 256, 0, stream>>>(W_hh_d, W_fc, W_hhd_b, W_fc_b);
    {
        int nx = SS * BB * 128 + BB * KE + BB * HH + (TT - 1) * BB * 128 + 32;
        prep_x<<<(nx + 255) / 256, 256, 0, stream>>>(inputs, targets, h0, E_enc, E_dec,
                                                     emb_pad, A_enc0, h_enc, A_dec, ce_sum);
    }

    // ---- encoder: 64 fused steps (double-buffered A) ----
    for (int s = 0; s < SS; ++s)
        enc_step<<<dim3(32, 4), 256, 0, stream>>>(Aenc[s & 1], Aenc[(s + 1) & 1], W_enc_big,
                                                  b_ih_e, b_hh_e, h_enc, emb_pad, lengths,
                                                  ctx_f, ctx_b, s);

    // ---- decoder input-side gates: one big GEMM ----
    fill_ctx<<<((TT - 1) * BB * HH) / 256, 256, 0, stream>>>(ctx_f, ctx_b, A_dec, h_dec, hb0);
    gemm128<ushort_t><<<dim3(G3 / 128, (TT - 1) * BB / 128), 256, 0, stream>>>(
        A_dec, W_dec_pad, gi_dec, KE, KE, KE, G3);

    // ---- decoder: 19 fused steps + fused logits/CE ----
    for (int t = 0; t < TT - 1; ++t) {
        dec_step<<<dim3(32, 4), 256, 0, stream>>>(hb[t & 1], hb[(t + 1) & 1], W_hhd_b,
                                                  gi_dec + (size_t)t * BB * G3,
                                                  b_ih_d, b_hh_d, h_dec);
        logits_ce<<<dim3(VV / 128, BB / 128), 256, 0, stream>>>(hb[(t + 1) & 1], W_fc_b, b_fc,
                                                                targets, part_max, part_sum, xt, t);
        ce_merge<<<64, 256, 0, stream>>>(part_max, part_sum, xt, ce_sum, t);
    }

    finalize<<<1, 64, 0, stream>>>(ce_sum, targets, (float*)d_out);
}